// Round 1
// baseline (496.202 us; speedup 1.0000x reference)
//
#include <hip/hip_runtime.h>
#include <cstdint>
#include <cstddef>

typedef __bf16 bfloat;
typedef __bf16 bf16x8 __attribute__((ext_vector_type(8)));
typedef __bf16 bf16x4 __attribute__((ext_vector_type(4)));
typedef float  f32x4  __attribute__((ext_vector_type(4)));

static constexpr int D  = 1024;
static constexpr int S  = 2048;
static constexpr int B  = 2;
static constexpr int H  = 16;
static constexpr int DH = 64;
static constexpr int M  = B * S;              // 4096 rows for all GEMMs
static constexpr int WMAT_N = 1024 * 1024;    // elements per weight matrix

#define MFMA_BF16(a, b, c) __builtin_amdgcn_mfma_f32_16x16x32_bf16((a), (b), (c), 0, 0, 0)

// async global->LDS, 16B per lane; LDS dest = wave-uniform base + lane*16
__device__ __forceinline__ void gl_lds16(const void* g, void* l) {
  __builtin_amdgcn_global_load_lds(
      (const __attribute__((address_space(1))) void*)g,
      (__attribute__((address_space(3))) void*)l, 16, 0, 0);
}

// ---------------- abs-sum reduce in f64 (threshold precision: borderline
// ternary flips shift scores by ~3 in an argmax-sharp softmax) -------------
__global__ void absum_kernel(const float* __restrict__ w0, const float* __restrict__ w1,
                             const float* __restrict__ w2, const float* __restrict__ w3,
                             double* __restrict__ sums) {
  int z = blockIdx.y;
  const float* w = (z == 0) ? w0 : (z == 1) ? w1 : (z == 2) ? w2 : w3;
  const float4* w4 = (const float4*)w;
  double s = 0.0;
  for (int i = blockIdx.x * blockDim.x + threadIdx.x; i < (WMAT_N / 4);
       i += gridDim.x * blockDim.x) {
    float4 v = w4[i];
    s += (double)fabsf(v.x) + (double)fabsf(v.y) + (double)fabsf(v.z) + (double)fabsf(v.w);
  }
  for (int off = 1; off < 64; off <<= 1) s += __shfl_xor(s, off, 64);
  __shared__ double ps[4];
  if ((threadIdx.x & 63) == 0) ps[threadIdx.x >> 6] = s;
  __syncthreads();
  if (threadIdx.x == 0) atomicAdd(&sums[z], ps[0] + ps[1] + ps[2] + ps[3]);
}

// ---------------- ternarize -> bf16 (-1/0/+1 exact in bf16) ----------------
__global__ void tern_kernel(const float* __restrict__ w0, const float* __restrict__ w1,
                            const float* __restrict__ w2, const float* __restrict__ w3,
                            bfloat* __restrict__ o0, bfloat* __restrict__ o1,
                            bfloat* __restrict__ o2, bfloat* __restrict__ o3,
                            const double* __restrict__ sums) {
  int z = blockIdx.y;
  const float* w = (z == 0) ? w0 : (z == 1) ? w1 : (z == 2) ? w2 : w3;
  bfloat* o = (z == 0) ? o0 : (z == 1) ? o1 : (z == 2) ? o2 : o3;
  double thr = sums[z] * (1.0 / (double)WMAT_N);
  const float4* w4 = (const float4*)w;
  for (int i = blockIdx.x * blockDim.x + threadIdx.x; i < (WMAT_N / 4);
       i += gridDim.x * blockDim.x) {
    float4 v = w4[i];
    bf16x4 r;
    r[0] = (bfloat)(((double)fabsf(v.x) > thr) ? (v.x > 0.f ? 1.f : -1.f) : 0.f);
    r[1] = (bfloat)(((double)fabsf(v.y) > thr) ? (v.y > 0.f ? 1.f : -1.f) : 0.f);
    r[2] = (bfloat)(((double)fabsf(v.z) > thr) ? (v.z > 0.f ? 1.f : -1.f) : 0.f);
    r[3] = (bfloat)(((double)fabsf(v.w) > thr) ? (v.w > 0.f ? 1.f : -1.f) : 0.f);
    *(bf16x4*)&o[(size_t)i * 4] = r;
  }
}

// ------------- fp32 -> bf16 hi (+ optional lo residual) split --------------
__global__ void splitcvt_kernel(const float* __restrict__ x, bfloat* __restrict__ hi,
                                bfloat* __restrict__ lo, int n4, int do_lo) {
  const float4* x4 = (const float4*)x;
  for (int i = blockIdx.x * blockDim.x + threadIdx.x; i < n4; i += gridDim.x * blockDim.x) {
    float4 v = x4[i];
    bf16x4 h;
    h[0] = (bfloat)v.x; h[1] = (bfloat)v.y; h[2] = (bfloat)v.z; h[3] = (bfloat)v.w;
    *(bf16x4*)&hi[(size_t)i * 4] = h;
    if (do_lo) {
      bf16x4 l;
      l[0] = (bfloat)(v.x - (float)h[0]);
      l[1] = (bfloat)(v.y - (float)h[1]);
      l[2] = (bfloat)(v.z - (float)h[2]);
      l[3] = (bfloat)(v.w - (float)h[3]);
      *(bf16x4*)&lo[(size_t)i * 4] = l;
    }
  }
}

// ---------------- GEMM: C[m,n] = sum_k (A0 [+A1])[m,k] * W[n,k] -----------
// m97-style: 128x128 tile, BK=32, global_load_lds(16B), 4 waves each 64x64.
// EPI: 0 = fp32 C, 1 = bf16 C, 2 = bf16 hi/lo split C.
template <int NSPLIT, int EPI>
__global__ __launch_bounds__(256) void gemm_bt(
    const bfloat* __restrict__ A0, const bfloat* __restrict__ A1,
    const bfloat* __restrict__ W, float* __restrict__ Cf,
    bfloat* __restrict__ Ch, bfloat* __restrict__ Cl) {
  constexpr int K = D;
  constexpr int N = D;
  __shared__ __align__(16) bfloat As0[128 * 32];
  __shared__ __align__(16) bfloat As1[(NSPLIT == 2) ? 128 * 32 : 8];
  __shared__ __align__(16) bfloat Ws[128 * 32];

  const int t = threadIdx.x;
  const int w = t >> 6, lane = t & 63;
  const int quad = lane >> 4, l16 = lane & 15;
  const int wm = w >> 1, wn = w & 1;
  const int m0 = blockIdx.y * 128, n0 = blockIdx.x * 128;

  f32x4 acc[4][4] = {};

  const int sr = t >> 2;        // staging row within 64
  const int sc = (t & 3) * 8;   // staging col (8 bf16 = 16B)

  const bfloat* pA0a = A0 + (size_t)(m0 + sr) * K + sc;
  const bfloat* pA0b = A0 + (size_t)(m0 + 64 + sr) * K + sc;
  const bfloat* pA1a = (NSPLIT == 2) ? A1 + (size_t)(m0 + sr) * K + sc : nullptr;
  const bfloat* pA1b = (NSPLIT == 2) ? A1 + (size_t)(m0 + 64 + sr) * K + sc : nullptr;
  const bfloat* pWa = W + (size_t)(n0 + sr) * K + sc;
  const bfloat* pWb = W + (size_t)(n0 + 64 + sr) * K + sc;

  for (int kk = 0; kk < K; kk += 32) {
    gl_lds16(pA0a + kk, As0 + w * 512);
    gl_lds16(pA0b + kk, As0 + 2048 + w * 512);
    if (NSPLIT == 2) {
      gl_lds16(pA1a + kk, As1 + w * 512);
      gl_lds16(pA1b + kk, As1 + 2048 + w * 512);
    }
    gl_lds16(pWa + kk, Ws + w * 512);
    gl_lds16(pWb + kk, Ws + 2048 + w * 512);
    __syncthreads();

    bf16x8 bfrag[4], afrag[4];
#pragma unroll
    for (int nt = 0; nt < 4; nt++)
      bfrag[nt] = *(const bf16x8*)&Ws[(wn * 64 + nt * 16 + l16) * 32 + quad * 8];
#pragma unroll
    for (int mt = 0; mt < 4; mt++)
      afrag[mt] = *(const bf16x8*)&As0[(wm * 64 + mt * 16 + l16) * 32 + quad * 8];
#pragma unroll
    for (int mt = 0; mt < 4; mt++)
#pragma unroll
      for (int nt = 0; nt < 4; nt++)
        acc[mt][nt] = MFMA_BF16(afrag[mt], bfrag[nt], acc[mt][nt]);
    if (NSPLIT == 2) {
#pragma unroll
      for (int mt = 0; mt < 4; mt++)
        afrag[mt] = *(const bf16x8*)&As1[(wm * 64 + mt * 16 + l16) * 32 + quad * 8];
#pragma unroll
      for (int mt = 0; mt < 4; mt++)
#pragma unroll
        for (int nt = 0; nt < 4; nt++)
          acc[mt][nt] = MFMA_BF16(afrag[mt], bfrag[nt], acc[mt][nt]);
    }
    __syncthreads();
  }

  // C/D layout (m89-verified): col = lane&15, row = quad*4 + reg
#pragma unroll
  for (int mt = 0; mt < 4; mt++) {
#pragma unroll
    for (int nt = 0; nt < 4; nt++) {
      const int row = m0 + wm * 64 + mt * 16 + quad * 4;
      const int col = n0 + wn * 64 + nt * 16 + l16;
#pragma unroll
      for (int rg = 0; rg < 4; rg++) {
        float vv = acc[mt][nt][rg];
        size_t idx = (size_t)(row + rg) * N + col;
        if (EPI == 0) {
          Cf[idx] = vv;
        } else if (EPI == 1) {
          Ch[idx] = (bfloat)vv;
        } else {
          bfloat hh = (bfloat)vv;
          Ch[idx] = hh;
          Cl[idx] = (bfloat)(vv - (float)hh);
        }
      }
    }
  }
}

// ---------------- flash attention, split-precision QK^T -------------------
// block = 4 waves = 64 Q rows (16/wave); 64-key tiles; online softmax.
__global__ __launch_bounds__(256) void flash_kernel(
    const bfloat* __restrict__ qh, const bfloat* __restrict__ ql,
    const bfloat* __restrict__ kh, const bfloat* __restrict__ kl,
    const bfloat* __restrict__ vm, bfloat* __restrict__ outp) {
  // +8 pad (stride 72 bf16 = 144B): conflict-free b128 within 16-lane groups
  __shared__ __align__(16) bfloat Qh[64 * 72], Ql[64 * 72];
  __shared__ __align__(16) bfloat Kh[64 * 72], Kl[64 * 72];
  __shared__ __align__(16) bfloat Vt[64 * 72];          // transposed: [dim][key]
  __shared__ __align__(16) bfloat Pm[4 * 16 * 72];      // per-wave P strips

  const int t = threadIdx.x;
  const int w = t >> 6, lane = t & 63;
  const int quad = lane >> 4, l16 = lane & 15;
  const int b = blockIdx.z, h = blockIdx.y;
  const int q0 = blockIdx.x * 64;
  const size_t base = (size_t)b * S * D + (size_t)h * DH;

  {  // stage Q hi/lo
    int e = t * 8;
#pragma unroll
    for (int i = 0; i < 2; i++) {
      int r = e >> 6, c = e & 63;
      *(uint4*)&Qh[r * 72 + c] = *(const uint4*)&qh[base + (size_t)(q0 + r) * D + c];
      *(uint4*)&Ql[r * 72 + c] = *(const uint4*)&ql[base + (size_t)(q0 + r) * D + c];
      e += 2048;
    }
  }

  f32x4 Oa[4] = {};
  float m_i[4], l_i[4];
#pragma unroll
  for (int i = 0; i < 4; i++) { m_i[i] = -3.0e38f; l_i[i] = 0.f; }

  const float SC = 0.125f * 1.44269504f;  // 1/sqrt(64) folded into exp2 scale

  for (int k0 = 0; k0 < S; k0 += 64) {
    __syncthreads();  // protect K/V/LDS from previous iteration's readers
    {
      int e = t * 8;
#pragma unroll
      for (int i = 0; i < 2; i++) {
        int r = e >> 6, c = e & 63;
        *(uint4*)&Kh[r * 72 + c] = *(const uint4*)&kh[base + (size_t)(k0 + r) * D + c];
        *(uint4*)&Kl[r * 72 + c] = *(const uint4*)&kl[base + (size_t)(k0 + r) * D + c];
        bf16x8 vv = *(const bf16x8*)&vm[base + (size_t)(k0 + r) * D + c];
#pragma unroll
        for (int j = 0; j < 8; j++) Vt[(c + j) * 72 + r] = vv[j];
        e += 2048;
      }
    }
    __syncthreads();

    // S = Qh*Kh + Ql*Kh + Qh*Kl  (split precision; lo*lo dropped)
    bf16x8 ah[2], al[2];
#pragma unroll
    for (int s2 = 0; s2 < 2; s2++) {
      ah[s2] = *(const bf16x8*)&Qh[(w * 16 + l16) * 72 + s2 * 32 + quad * 8];
      al[s2] = *(const bf16x8*)&Ql[(w * 16 + l16) * 72 + s2 * 32 + quad * 8];
    }
    f32x4 sf[4];
#pragma unroll
    for (int nt = 0; nt < 4; nt++) {
      f32x4 acc = {};
#pragma unroll
      for (int s2 = 0; s2 < 2; s2++) {
        bf16x8 bh = *(const bf16x8*)&Kh[(nt * 16 + l16) * 72 + s2 * 32 + quad * 8];
        bf16x8 bl = *(const bf16x8*)&Kl[(nt * 16 + l16) * 72 + s2 * 32 + quad * 8];
        acc = MFMA_BF16(ah[s2], bh, acc);
        acc = MFMA_BF16(al[s2], bh, acc);
        acc = MFMA_BF16(ah[s2], bl, acc);
      }
      sf[nt] = acc;
    }

#pragma unroll
    for (int nt = 0; nt < 4; nt++)
#pragma unroll
      for (int rg = 0; rg < 4; rg++) sf[nt][rg] *= SC;

    // online softmax; row = quad*4+rg lives on the 16 lanes of this quad
#pragma unroll
    for (int rg = 0; rg < 4; rg++) {
      float mm = fmaxf(fmaxf(sf[0][rg], sf[1][rg]), fmaxf(sf[2][rg], sf[3][rg]));
#pragma unroll
      for (int off = 1; off < 16; off <<= 1) mm = fmaxf(mm, __shfl_xor(mm, off, 64));
      float mnew = fmaxf(m_i[rg], mm);
      float alpha = exp2f(m_i[rg] - mnew);
      m_i[rg] = mnew;
      float rs = 0.f;
#pragma unroll
      for (int nt = 0; nt < 4; nt++) {
        float p = exp2f(sf[nt][rg] - mnew);
        sf[nt][rg] = p;
        rs += p;
      }
#pragma unroll
      for (int off = 1; off < 16; off <<= 1) rs += __shfl_xor(rs, off, 64);
      l_i[rg] = l_i[rg] * alpha + rs;
#pragma unroll
      for (int nt = 0; nt < 4; nt++) Oa[nt][rg] *= alpha;
    }

    // P: C-layout -> A-layout via LDS (wave-private strip)
#pragma unroll
    for (int nt = 0; nt < 4; nt++)
#pragma unroll
      for (int rg = 0; rg < 4; rg++)
        Pm[(w * 16 + quad * 4 + rg) * 72 + nt * 16 + l16] = (bfloat)sf[nt][rg];
    __syncthreads();

    // O += P @ V   (B frags from transposed V: contiguous keys)
#pragma unroll
    for (int s2 = 0; s2 < 2; s2++) {
      bf16x8 pa = *(const bf16x8*)&Pm[(w * 16 + l16) * 72 + s2 * 32 + quad * 8];
#pragma unroll
      for (int nt = 0; nt < 4; nt++) {
        bf16x8 vb = *(const bf16x8*)&Vt[(nt * 16 + l16) * 72 + s2 * 32 + quad * 8];
        Oa[nt] = MFMA_BF16(pa, vb, Oa[nt]);
      }
    }
  }

#pragma unroll
  for (int rg = 0; rg < 4; rg++) {
    float inv = 1.0f / l_i[rg];
#pragma unroll
    for (int nt = 0; nt < 4; nt++) {
      outp[base + (size_t)(q0 + w * 16 + quad * 4 + rg) * D + nt * 16 + l16] =
          (bfloat)(Oa[nt][rg] * inv);
    }
  }
}

extern "C" void kernel_launch(void* const* d_in, const int* in_sizes, int n_in,
                              void* d_out, int out_size, void* d_ws, size_t ws_size,
                              hipStream_t stream) {
  const float* q_in = (const float*)d_in[0];
  const float* k_in = (const float*)d_in[1];
  const float* v_in = (const float*)d_in[2];
  const float* wq = (const float*)d_in[3];
  const float* wk = (const float*)d_in[4];
  const float* wv = (const float*)d_in[5];
  const float* wo = (const float*)d_in[6];
  float* outp = (float*)d_out;
  char* ws = (char*)d_ws;

  constexpr size_t WBYTES = (size_t)WMAT_N * 2;  // 2 MB per ternary weight
  constexpr size_t XBYTES = (size_t)M * D * 2;   // 8 MB per bf16 activation
  size_t off = 0;
  double* sums = (double*)(ws + off); off += 256;
  bfloat* wqt = (bfloat*)(ws + off); off += WBYTES;
  bfloat* wkt = (bfloat*)(ws + off); off += WBYTES;
  bfloat* wvt = (bfloat*)(ws + off); off += WBYTES;
  bfloat* wot = (bfloat*)(ws + off); off += WBYTES;
  bfloat* xqh = (bfloat*)(ws + off); off += XBYTES;
  bfloat* xql = (bfloat*)(ws + off); off += XBYTES;
  bfloat* xkh = (bfloat*)(ws + off); off += XBYTES;
  bfloat* xkl = (bfloat*)(ws + off); off += XBYTES;
  bfloat* xvh = (bfloat*)(ws + off); off += XBYTES;
  bfloat* qmh = (bfloat*)(ws + off); off += XBYTES;
  bfloat* qml = (bfloat*)(ws + off); off += XBYTES;
  bfloat* kmh = (bfloat*)(ws + off); off += XBYTES;
  bfloat* kml = (bfloat*)(ws + off); off += XBYTES;
  bfloat* vmm = (bfloat*)(ws + off); off += XBYTES;
  bfloat* attn = xqh;  // xqh is dead after the q projection; reuse for attn out

  hipMemsetAsync(sums, 0, 4 * sizeof(double), stream);
  absum_kernel<<<dim3(128, 4), 256, 0, stream>>>(wq, wk, wv, wo, sums);
  tern_kernel<<<dim3(128, 4), 256, 0, stream>>>(wq, wk, wv, wo, wqt, wkt, wvt, wot, sums);
  const int n4 = M * D / 4;
  splitcvt_kernel<<<512, 256, 0, stream>>>(q_in, xqh, xql, n4, 1);
  splitcvt_kernel<<<512, 256, 0, stream>>>(k_in, xkh, xkl, n4, 1);
  splitcvt_kernel<<<512, 256, 0, stream>>>(v_in, xvh, nullptr, n4, 0);
  dim3 gg(D / 128, M / 128);  // (8, 32) = 256 blocks
  gemm_bt<2, 2><<<gg, 256, 0, stream>>>(xqh, xql, wqt, nullptr, qmh, qml);
  gemm_bt<2, 2><<<gg, 256, 0, stream>>>(xkh, xkl, wkt, nullptr, kmh, kml);
  gemm_bt<1, 1><<<gg, 256, 0, stream>>>(xvh, nullptr, wvt, nullptr, vmm, nullptr);
  flash_kernel<<<dim3(S / 64, H, B), 256, 0, stream>>>(qmh, qml, kmh, kml, vmm, attn);
  gemm_bt<1, 0><<<gg, 256, 0, stream>>>(attn, nullptr, wot, outp, nullptr, nullptr);
}

// Round 2
// 379.960 us; speedup vs baseline: 1.3059x; 1.3059x over previous
//
#include <hip/hip_runtime.h>
#include <cstdint>
#include <cstddef>

typedef __bf16 bfloat;
typedef __bf16 bf16x8 __attribute__((ext_vector_type(8)));
typedef __bf16 bf16x4 __attribute__((ext_vector_type(4)));
typedef float  f32x4  __attribute__((ext_vector_type(4)));

static constexpr int D  = 1024;
static constexpr int S  = 2048;
static constexpr int B  = 2;
static constexpr int H  = 16;
static constexpr int DH = 64;
static constexpr int M  = B * S;
static constexpr int WMAT_N = 1024 * 1024;

#define MFMA_BF16(a, b, c) __builtin_amdgcn_mfma_f32_16x16x32_bf16((a), (b), (c), 0, 0, 0)

__device__ __forceinline__ void gl_lds16(const void* g, void* l) {
  __builtin_amdgcn_global_load_lds(
      (const __attribute__((address_space(1))) void*)g,
      (__attribute__((address_space(3))) void*)l, 16, 0, 0);
}

// ---------------- abs-sum reduce in f64 ----------------
__global__ void absum_kernel(const float* __restrict__ w0, const float* __restrict__ w1,
                             const float* __restrict__ w2, const float* __restrict__ w3,
                             double* __restrict__ sums) {
  int z = blockIdx.y;
  const float* w = (z == 0) ? w0 : (z == 1) ? w1 : (z == 2) ? w2 : w3;
  const float4* w4 = (const float4*)w;
  double s = 0.0;
  for (int i = blockIdx.x * blockDim.x + threadIdx.x; i < (WMAT_N / 4);
       i += gridDim.x * blockDim.x) {
    float4 v = w4[i];
    s += (double)fabsf(v.x) + (double)fabsf(v.y) + (double)fabsf(v.z) + (double)fabsf(v.w);
  }
  for (int off = 1; off < 64; off <<= 1) s += __shfl_xor(s, off, 64);
  __shared__ double ps[4];
  if ((threadIdx.x & 63) == 0) ps[threadIdx.x >> 6] = s;
  __syncthreads();
  if (threadIdx.x == 0) atomicAdd(&sums[z], ps[0] + ps[1] + ps[2] + ps[3]);
}

// ---------------- ternarize -> bf16 ----------------
__global__ void tern_kernel(const float* __restrict__ w0, const float* __restrict__ w1,
                            const float* __restrict__ w2, const float* __restrict__ w3,
                            bfloat* __restrict__ o0, bfloat* __restrict__ o1,
                            bfloat* __restrict__ o2, bfloat* __restrict__ o3,
                            const double* __restrict__ sums) {
  int z = blockIdx.y;
  const float* w = (z == 0) ? w0 : (z == 1) ? w1 : (z == 2) ? w2 : w3;
  bfloat* o = (z == 0) ? o0 : (z == 1) ? o1 : (z == 2) ? o2 : o3;
  double thr = sums[z] * (1.0 / (double)WMAT_N);
  const float4* w4 = (const float4*)w;
  for (int i = blockIdx.x * blockDim.x + threadIdx.x; i < (WMAT_N / 4);
       i += gridDim.x * blockDim.x) {
    float4 v = w4[i];
    bf16x4 r;
    r[0] = (bfloat)(((double)fabsf(v.x) > thr) ? (v.x > 0.f ? 1.f : -1.f) : 0.f);
    r[1] = (bfloat)(((double)fabsf(v.y) > thr) ? (v.y > 0.f ? 1.f : -1.f) : 0.f);
    r[2] = (bfloat)(((double)fabsf(v.z) > thr) ? (v.z > 0.f ? 1.f : -1.f) : 0.f);
    r[3] = (bfloat)(((double)fabsf(v.w) > thr) ? (v.w > 0.f ? 1.f : -1.f) : 0.f);
    *(bf16x4*)&o[(size_t)i * 4] = r;
  }
}

// ------------- fp32 -> bf16 hi (+ optional lo residual) -------------
__global__ void splitcvt_kernel(const float* __restrict__ x, bfloat* __restrict__ hi,
                                bfloat* __restrict__ lo, int n4, int do_lo) {
  const float4* x4 = (const float4*)x;
  for (int i = blockIdx.x * blockDim.x + threadIdx.x; i < n4; i += gridDim.x * blockDim.x) {
    float4 v = x4[i];
    bf16x4 h;
    h[0] = (bfloat)v.x; h[1] = (bfloat)v.y; h[2] = (bfloat)v.z; h[3] = (bfloat)v.w;
    *(bf16x4*)&hi[(size_t)i * 4] = h;
    if (do_lo) {
      bf16x4 l;
      l[0] = (bfloat)(v.x - (float)h[0]);
      l[1] = (bfloat)(v.y - (float)h[1]);
      l[2] = (bfloat)(v.z - (float)h[2]);
      l[3] = (bfloat)(v.w - (float)h[3]);
      *(bf16x4*)&lo[(size_t)i * 4] = l;
    }
  }
}

// --------- V transpose: [B*S][D] -> [B][D][S] (one-shot, ~32 MB) ---------
__global__ __launch_bounds__(256) void transpose_v(const bfloat* __restrict__ in,
                                                   bfloat* __restrict__ out) {
  __shared__ __align__(16) bfloat T[64 * 72];
  const int t = threadIdx.x;
  const int s0 = blockIdx.x * 64, n0 = blockIdx.y * 64, b = blockIdx.z;
#pragma unroll
  for (int p = 0; p < 2; p++) {
    int e = t * 8 + p * 2048;
    int r = e >> 6, cc = e & 63;  // r = token row, cc = feature col
    bf16x8 v = *(const bf16x8*)&in[(size_t)(b * S + s0 + r) * D + n0 + cc];
#pragma unroll
    for (int j = 0; j < 8; j++) T[(cc + j) * 72 + r] = v[j];
  }
  __syncthreads();
#pragma unroll
  for (int p = 0; p < 2; p++) {
    int e = t * 8 + p * 2048;
    int f = e >> 6, cc = e & 63;  // f = feature row, cc = token col
    bf16x8 v = *(const bf16x8*)&T[f * 72 + cc];
    *(bf16x8*)&out[(size_t)b * D * S + (size_t)(n0 + f) * S + s0 + cc] = v;
  }
}

// ---------------- GEMM: C[m,n] = sum_k (A0 [+A1])[m,k] * W[n,k] -----------
// 64x64 tile, BK=32, gl_lds16 staging with 16B XOR swizzle (2-way clean reads),
// grid (16,64)=1024 blocks -> 4 blocks/CU. EPI: 0=f32, 1=bf16, 2=bf16 hi/lo.
template <int NSPLIT, int EPI>
__global__ __launch_bounds__(256, 4) void gemm_bt(
    const bfloat* __restrict__ A0, const bfloat* __restrict__ A1,
    const bfloat* __restrict__ W, float* __restrict__ Cf,
    bfloat* __restrict__ Ch, bfloat* __restrict__ Cl) {
  constexpr int K = D;
  constexpr int N = D;
  __shared__ __align__(16) bfloat As0[64 * 32];
  __shared__ __align__(16) bfloat As1[(NSPLIT == 2) ? 64 * 32 : 8];
  __shared__ __align__(16) bfloat Ws[64 * 32];

  const int t = threadIdx.x;
  const int w = t >> 6, lane = t & 63;
  const int quad = lane >> 4, l16 = lane & 15;
  const int wm = w >> 1, wn = w & 1;
  const int m0 = blockIdx.y * 64, n0 = blockIdx.x * 64;

  f32x4 acc[2][2] = {};

  // staging: wave w covers rows w*16..w*16+15, 4 chunks of 16B per row
  const int sr = w * 16 + (lane >> 2);
  const int sc = (lane & 3) ^ ((sr >> 1) & 3);  // swizzled logical chunk

  const bfloat* pA0 = A0 + (size_t)(m0 + sr) * K + sc * 8;
  const bfloat* pA1 = (NSPLIT == 2) ? A1 + (size_t)(m0 + sr) * K + sc * 8 : nullptr;
  const bfloat* pW = W + (size_t)(n0 + sr) * K + sc * 8;
  const int ldso = w * 16 * 32;

  for (int kk = 0; kk < K; kk += 32) {
    gl_lds16(pA0 + kk, As0 + ldso);
    if (NSPLIT == 2) gl_lds16(pA1 + kk, As1 + ldso);
    gl_lds16(pW + kk, Ws + ldso);
    __syncthreads();

    bf16x8 af[2], bf[2];
#pragma unroll
    for (int i = 0; i < 2; i++) {
      int ar = wm * 32 + i * 16 + l16;
      af[i] = *(const bf16x8*)&As0[ar * 32 + ((quad ^ ((ar >> 1) & 3)) * 8)];
      int br = wn * 32 + i * 16 + l16;
      bf[i] = *(const bf16x8*)&Ws[br * 32 + ((quad ^ ((br >> 1) & 3)) * 8)];
    }
#pragma unroll
    for (int mt = 0; mt < 2; mt++)
#pragma unroll
      for (int nt = 0; nt < 2; nt++)
        acc[mt][nt] = MFMA_BF16(af[mt], bf[nt], acc[mt][nt]);
    if (NSPLIT == 2) {
#pragma unroll
      for (int i = 0; i < 2; i++) {
        int ar = wm * 32 + i * 16 + l16;
        af[i] = *(const bf16x8*)&As1[ar * 32 + ((quad ^ ((ar >> 1) & 3)) * 8)];
      }
#pragma unroll
      for (int mt = 0; mt < 2; mt++)
#pragma unroll
        for (int nt = 0; nt < 2; nt++)
          acc[mt][nt] = MFMA_BF16(af[mt], bf[nt], acc[mt][nt]);
    }
    __syncthreads();
  }

#pragma unroll
  for (int mt = 0; mt < 2; mt++) {
#pragma unroll
    for (int nt = 0; nt < 2; nt++) {
      const int row = m0 + wm * 32 + mt * 16 + quad * 4;
      const int col = n0 + wn * 32 + nt * 16 + l16;
#pragma unroll
      for (int rg = 0; rg < 4; rg++) {
        float vv = acc[mt][nt][rg];
        size_t idx = (size_t)(row + rg) * N + col;
        if (EPI == 0) {
          Cf[idx] = vv;
        } else if (EPI == 1) {
          Ch[idx] = (bfloat)vv;
        } else {
          bfloat hh = (bfloat)vv;
          Ch[idx] = hh;
          Cl[idx] = (bfloat)(vv - (float)hh);
        }
      }
    }
  }
}

// ---------------- flash attention v2 ----------------
// Register-resident Q frags; K/V staged via gl_lds16 with XOR swizzle;
// V pre-transposed globally. LDS = 32 KB -> 4 blocks/CU (grid = 1024 = 4/CU).
__global__ __launch_bounds__(256, 4) void flash_kernel(
    const bfloat* __restrict__ qh, const bfloat* __restrict__ ql,
    const bfloat* __restrict__ kh, const bfloat* __restrict__ kl,
    const bfloat* __restrict__ vt, bfloat* __restrict__ outp) {
  __shared__ __align__(16) bfloat Kh[64 * 64];
  __shared__ __align__(16) bfloat Kl[64 * 64];
  __shared__ __align__(16) bfloat Vt[64 * 64];
  __shared__ __align__(16) bfloat Pm[64 * 64];

  const int t = threadIdx.x;
  const int w = t >> 6, lane = t & 63;
  const int quad = lane >> 4, l16 = lane & 15;
  const int b = blockIdx.z, h = blockIdx.y;
  const int q0 = blockIdx.x * 64;
  const size_t base = (size_t)b * S * D + (size_t)h * DH;       // [b][s][n]
  const size_t vbase = (size_t)b * D * S + (size_t)h * DH * S;  // [b][n][s]

  const int ssr = lane >> 3;  // staging row within 8-row group
  const int spc = lane & 7;   // physical chunk -> logical chunk = spc ^ (row&7)

  // stage Q hi/lo through K buffers, pull frags to registers (k0-invariant)
#pragma unroll
  for (int g = 0; g < 2; g++) {
    int r = w * 16 + g * 8 + ssr;
    int c = spc ^ (r & 7);
    gl_lds16(qh + base + (size_t)(q0 + r) * D + c * 8, Kh + (w * 16 + g * 8) * 64);
    gl_lds16(ql + base + (size_t)(q0 + r) * D + c * 8, Kl + (w * 16 + g * 8) * 64);
  }
  __syncthreads();
  bf16x8 ah[2], al[2];
  {
    int row = w * 16 + l16;
#pragma unroll
    for (int s2 = 0; s2 < 2; s2++) {
      ah[s2] = *(const bf16x8*)&Kh[row * 64 + (((s2 * 4 + quad) ^ (row & 7)) * 8)];
      al[s2] = *(const bf16x8*)&Kl[row * 64 + (((s2 * 4 + quad) ^ (row & 7)) * 8)];
    }
  }

  f32x4 Oa[4] = {};
  float m_i[4], l_i[4];
#pragma unroll
  for (int i = 0; i < 4; i++) { m_i[i] = -3.0e38f; l_i[i] = 0.f; }

  const float SC = 0.125f * 1.44269504f;  // 1/sqrt(64) folded into exp2

  for (int k0 = 0; k0 < S; k0 += 64) {
    __syncthreads();  // prev iter's frag reads (and prologue Q reads) done
#pragma unroll
    for (int g = 0; g < 2; g++) {
      int r = w * 16 + g * 8 + ssr;
      int c = spc ^ (r & 7);
      bfloat* ldsb = (bfloat*)0 + (w * 16 + g * 8) * 64;  // offset helper (elems)
      (void)ldsb;
      int lo = (w * 16 + g * 8) * 64;
      gl_lds16(kh + base + (size_t)(k0 + r) * D + c * 8, Kh + lo);
      gl_lds16(kl + base + (size_t)(k0 + r) * D + c * 8, Kl + lo);
      gl_lds16(vt + vbase + (size_t)r * S + k0 + c * 8, Vt + lo);
    }
    __syncthreads();

    // S = Qh*Kh + Ql*Kh + Qh*Kl
    f32x4 sf[4];
#pragma unroll
    for (int nt = 0; nt < 4; nt++) {
      f32x4 acc = {};
      int row = nt * 16 + l16;
#pragma unroll
      for (int s2 = 0; s2 < 2; s2++) {
        bf16x8 bh = *(const bf16x8*)&Kh[row * 64 + (((s2 * 4 + quad) ^ (row & 7)) * 8)];
        bf16x8 bl = *(const bf16x8*)&Kl[row * 64 + (((s2 * 4 + quad) ^ (row & 7)) * 8)];
        acc = MFMA_BF16(ah[s2], bh, acc);
        acc = MFMA_BF16(al[s2], bh, acc);
        acc = MFMA_BF16(ah[s2], bl, acc);
      }
      sf[nt] = acc;
    }

#pragma unroll
    for (int nt = 0; nt < 4; nt++)
#pragma unroll
      for (int rg = 0; rg < 4; rg++) sf[nt][rg] *= SC;

    // online softmax; row quad*4+rg lives on the 16 lanes of this quad
#pragma unroll
    for (int rg = 0; rg < 4; rg++) {
      float mm = fmaxf(fmaxf(sf[0][rg], sf[1][rg]), fmaxf(sf[2][rg], sf[3][rg]));
#pragma unroll
      for (int off = 1; off < 16; off <<= 1) mm = fmaxf(mm, __shfl_xor(mm, off, 64));
      float mnew = fmaxf(m_i[rg], mm);
      float alpha = exp2f(m_i[rg] - mnew);
      m_i[rg] = mnew;
      float rs = 0.f;
#pragma unroll
      for (int nt = 0; nt < 4; nt++) {
        float p = exp2f(sf[nt][rg] - mnew);
        sf[nt][rg] = p;
        rs += p;
      }
#pragma unroll
      for (int off = 1; off < 16; off <<= 1) rs += __shfl_xor(rs, off, 64);
      l_i[rg] = l_i[rg] * alpha + rs;
#pragma unroll
      for (int nt = 0; nt < 4; nt++) Oa[nt][rg] *= alpha;
    }

    // P: C-layout -> A-layout via wave-private LDS strip (swizzled, 2-way clean)
#pragma unroll
    for (int nt = 0; nt < 4; nt++)
#pragma unroll
      for (int rg = 0; rg < 4; rg++) {
        int row = w * 16 + quad * 4 + rg;
        int col = nt * 16 + l16;
        Pm[row * 64 + (((col >> 3) ^ (row & 7)) * 8) + (col & 7)] = (bfloat)sf[nt][rg];
      }

    // O += P @ V  (no barrier: Pm strip is wave-private)
    int prow = w * 16 + l16;
#pragma unroll
    for (int s2 = 0; s2 < 2; s2++) {
      bf16x8 pa = *(const bf16x8*)&Pm[prow * 64 + (((s2 * 4 + quad) ^ (prow & 7)) * 8)];
#pragma unroll
      for (int nt = 0; nt < 4; nt++) {
        int vrow = nt * 16 + l16;
        bf16x8 vb = *(const bf16x8*)&Vt[vrow * 64 + (((s2 * 4 + quad) ^ (vrow & 7)) * 8)];
        Oa[nt] = MFMA_BF16(pa, vb, Oa[nt]);
      }
    }
  }

#pragma unroll
  for (int rg = 0; rg < 4; rg++) {
    float inv = 1.0f / l_i[rg];
#pragma unroll
    for (int nt = 0; nt < 4; nt++) {
      outp[base + (size_t)(q0 + w * 16 + quad * 4 + rg) * D + nt * 16 + l16] =
          (bfloat)(Oa[nt][rg] * inv);
    }
  }
}

extern "C" void kernel_launch(void* const* d_in, const int* in_sizes, int n_in,
                              void* d_out, int out_size, void* d_ws, size_t ws_size,
                              hipStream_t stream) {
  const float* q_in = (const float*)d_in[0];
  const float* k_in = (const float*)d_in[1];
  const float* v_in = (const float*)d_in[2];
  const float* wq = (const float*)d_in[3];
  const float* wk = (const float*)d_in[4];
  const float* wv = (const float*)d_in[5];
  const float* wo = (const float*)d_in[6];
  float* outp = (float*)d_out;
  char* ws = (char*)d_ws;

  constexpr size_t WBYTES = (size_t)WMAT_N * 2;
  constexpr size_t XBYTES = (size_t)M * D * 2;
  size_t off = 0;
  double* sums = (double*)(ws + off); off += 256;
  bfloat* wqt = (bfloat*)(ws + off); off += WBYTES;
  bfloat* wkt = (bfloat*)(ws + off); off += WBYTES;
  bfloat* wvt = (bfloat*)(ws + off); off += WBYTES;
  bfloat* wot = (bfloat*)(ws + off); off += WBYTES;
  bfloat* xqh = (bfloat*)(ws + off); off += XBYTES;
  bfloat* xql = (bfloat*)(ws + off); off += XBYTES;
  bfloat* xkh = (bfloat*)(ws + off); off += XBYTES;
  bfloat* xkl = (bfloat*)(ws + off); off += XBYTES;
  bfloat* xvh = (bfloat*)(ws + off); off += XBYTES;
  bfloat* qmh = (bfloat*)(ws + off); off += XBYTES;
  bfloat* qml = (bfloat*)(ws + off); off += XBYTES;
  bfloat* kmh = (bfloat*)(ws + off); off += XBYTES;
  bfloat* kml = (bfloat*)(ws + off); off += XBYTES;
  bfloat* vmm = (bfloat*)(ws + off); off += XBYTES;
  bfloat* attn = xqh;  // dead after q projection
  bfloat* vtr = xvh;   // dead after v projection; reused for V^T [B][D][S]

  hipMemsetAsync(sums, 0, 4 * sizeof(double), stream);
  absum_kernel<<<dim3(128, 4), 256, 0, stream>>>(wq, wk, wv, wo, sums);
  tern_kernel<<<dim3(128, 4), 256, 0, stream>>>(wq, wk, wv, wo, wqt, wkt, wvt, wot, sums);
  const int n4 = M * D / 4;
  splitcvt_kernel<<<512, 256, 0, stream>>>(q_in, xqh, xql, n4, 1);
  splitcvt_kernel<<<512, 256, 0, stream>>>(k_in, xkh, xkl, n4, 1);
  splitcvt_kernel<<<512, 256, 0, stream>>>(v_in, xvh, nullptr, n4, 0);
  dim3 gg(D / 64, M / 64);  // (16, 64) = 1024 blocks = 4/CU
  gemm_bt<2, 2><<<gg, 256, 0, stream>>>(xqh, xql, wqt, nullptr, qmh, qml);
  gemm_bt<2, 2><<<gg, 256, 0, stream>>>(xkh, xkl, wkt, nullptr, kmh, kml);
  gemm_bt<1, 1><<<gg, 256, 0, stream>>>(xvh, nullptr, wvt, nullptr, vmm, nullptr);
  transpose_v<<<dim3(S / 64, D / 64, B), 256, 0, stream>>>(vmm, vtr);
  flash_kernel<<<dim3(S / 64, H, B), 256, 0, stream>>>(qmh, qml, kmh, kml, vtr, attn);
  gemm_bt<1, 0><<<gg, 256, 0, stream>>>(attn, nullptr, wot, outp, nullptr, nullptr);
}

// Round 3
// 328.713 us; speedup vs baseline: 1.5095x; 1.1559x over previous
//
#include <hip/hip_runtime.h>
#include <cstdint>
#include <cstddef>

typedef __bf16 bfloat;
typedef __bf16 bf16x8 __attribute__((ext_vector_type(8)));
typedef __bf16 bf16x4 __attribute__((ext_vector_type(4)));
typedef float  f32x4  __attribute__((ext_vector_type(4)));

static constexpr int D  = 1024;
static constexpr int S  = 2048;
static constexpr int B  = 2;
static constexpr int H  = 16;
static constexpr int DH = 64;
static constexpr int M  = B * S;
static constexpr int WMAT_N = 1024 * 1024;

#define MFMA_BF16(a, b, c) __builtin_amdgcn_mfma_f32_16x16x32_bf16((a), (b), (c), 0, 0, 0)

__device__ __forceinline__ void gl_lds16(const void* g, void* l) {
  __builtin_amdgcn_global_load_lds(
      (const __attribute__((address_space(1))) void*)g,
      (__attribute__((address_space(3))) void*)l, 16, 0, 0);
}

// ---------------- abs-sum reduce in f64 ----------------
__global__ void absum_kernel(const float* __restrict__ w0, const float* __restrict__ w1,
                             const float* __restrict__ w2, const float* __restrict__ w3,
                             double* __restrict__ sums) {
  int z = blockIdx.y;
  const float* w = (z == 0) ? w0 : (z == 1) ? w1 : (z == 2) ? w2 : w3;
  const float4* w4 = (const float4*)w;
  double s = 0.0;
  for (int i = blockIdx.x * blockDim.x + threadIdx.x; i < (WMAT_N / 4);
       i += gridDim.x * blockDim.x) {
    float4 v = w4[i];
    s += (double)fabsf(v.x) + (double)fabsf(v.y) + (double)fabsf(v.z) + (double)fabsf(v.w);
  }
  for (int off = 1; off < 64; off <<= 1) s += __shfl_xor(s, off, 64);
  __shared__ double ps[4];
  if ((threadIdx.x & 63) == 0) ps[threadIdx.x >> 6] = s;
  __syncthreads();
  if (threadIdx.x == 0) atomicAdd(&sums[z], ps[0] + ps[1] + ps[2] + ps[3]);
}

// ---------------- ternarize -> bf16 ----------------
__global__ void tern_kernel(const float* __restrict__ w0, const float* __restrict__ w1,
                            const float* __restrict__ w2, const float* __restrict__ w3,
                            bfloat* __restrict__ o0, bfloat* __restrict__ o1,
                            bfloat* __restrict__ o2, bfloat* __restrict__ o3,
                            const double* __restrict__ sums) {
  int z = blockIdx.y;
  const float* w = (z == 0) ? w0 : (z == 1) ? w1 : (z == 2) ? w2 : w3;
  bfloat* o = (z == 0) ? o0 : (z == 1) ? o1 : (z == 2) ? o2 : o3;
  double thr = sums[z] * (1.0 / (double)WMAT_N);
  const float4* w4 = (const float4*)w;
  for (int i = blockIdx.x * blockDim.x + threadIdx.x; i < (WMAT_N / 4);
       i += gridDim.x * blockDim.x) {
    float4 v = w4[i];
    bf16x4 r;
    r[0] = (bfloat)(((double)fabsf(v.x) > thr) ? (v.x > 0.f ? 1.f : -1.f) : 0.f);
    r[1] = (bfloat)(((double)fabsf(v.y) > thr) ? (v.y > 0.f ? 1.f : -1.f) : 0.f);
    r[2] = (bfloat)(((double)fabsf(v.z) > thr) ? (v.z > 0.f ? 1.f : -1.f) : 0.f);
    r[3] = (bfloat)(((double)fabsf(v.w) > thr) ? (v.w > 0.f ? 1.f : -1.f) : 0.f);
    *(bf16x4*)&o[(size_t)i * 4] = r;
  }
}

// ------------- fp32 -> bf16 hi (+ lo residual) for q,k,v in one launch -----
__global__ void splitcvt3_kernel(const float* __restrict__ qx, const float* __restrict__ kx,
                                 const float* __restrict__ vx, bfloat* __restrict__ qhi,
                                 bfloat* __restrict__ qlo, bfloat* __restrict__ khi,
                                 bfloat* __restrict__ klo, bfloat* __restrict__ vhi) {
  int z = blockIdx.y;
  const float* x = (z == 0) ? qx : (z == 1) ? kx : vx;
  bfloat* hi = (z == 0) ? qhi : (z == 1) ? khi : vhi;
  bfloat* lo = (z == 0) ? qlo : (z == 1) ? klo : nullptr;
  const int n4 = M * D / 4;
  const float4* x4 = (const float4*)x;
  for (int i = blockIdx.x * blockDim.x + threadIdx.x; i < n4; i += gridDim.x * blockDim.x) {
    float4 v = x4[i];
    bf16x4 h;
    h[0] = (bfloat)v.x; h[1] = (bfloat)v.y; h[2] = (bfloat)v.z; h[3] = (bfloat)v.w;
    *(bf16x4*)&hi[(size_t)i * 4] = h;
    if (z < 2) {
      bf16x4 l;
      l[0] = (bfloat)(v.x - (float)h[0]);
      l[1] = (bfloat)(v.y - (float)h[1]);
      l[2] = (bfloat)(v.z - (float)h[2]);
      l[3] = (bfloat)(v.w - (float)h[3]);
      *(bf16x4*)&lo[(size_t)i * 4] = l;
    }
  }
}

// --------- V transpose: [B*S][D] -> [B][D][S] ---------
__global__ __launch_bounds__(256) void transpose_v(const bfloat* __restrict__ in,
                                                   bfloat* __restrict__ out) {
  __shared__ __align__(16) bfloat T[64 * 72];
  const int t = threadIdx.x;
  const int s0 = blockIdx.x * 64, n0 = blockIdx.y * 64, b = blockIdx.z;
#pragma unroll
  for (int p = 0; p < 2; p++) {
    int e = t * 8 + p * 2048;
    int r = e >> 6, cc = e & 63;
    bf16x8 v = *(const bf16x8*)&in[(size_t)(b * S + s0 + r) * D + n0 + cc];
#pragma unroll
    for (int j = 0; j < 8; j++) T[(cc + j) * 72 + r] = v[j];
  }
  __syncthreads();
#pragma unroll
  for (int p = 0; p < 2; p++) {
    int e = t * 8 + p * 2048;
    int f = e >> 6, cc = e & 63;
    bf16x8 v = *(const bf16x8*)&T[f * 72 + cc];
    *(bf16x8*)&out[(size_t)b * D * S + (size_t)(n0 + f) * S + s0 + cc] = v;
  }
}

// -------- fused q/k/v projection: blockIdx.z selects matrix ---------------
// 128x128 tile, BK=32, m97 structure (round-1 verified). grid (8,32,3)=768.
// q: split-A 2-pass, epilogue x softmax-scale, split hi/lo out.
// k: split-A 2-pass, split hi/lo out.  v: 1-pass, bf16 out.
__global__ __launch_bounds__(256) void qkv_gemm(
    const bfloat* __restrict__ xqh, const bfloat* __restrict__ xql,
    const bfloat* __restrict__ xkh, const bfloat* __restrict__ xkl,
    const bfloat* __restrict__ xvh, const bfloat* __restrict__ wqt,
    const bfloat* __restrict__ wkt, const bfloat* __restrict__ wvt,
    bfloat* __restrict__ qmh, bfloat* __restrict__ qml,
    bfloat* __restrict__ kmh, bfloat* __restrict__ kml, bfloat* __restrict__ vmm) {
  constexpr int K = D;
  constexpr int N = D;
  __shared__ __align__(16) bfloat As0[128 * 32];
  __shared__ __align__(16) bfloat As1[128 * 32];
  __shared__ __align__(16) bfloat Ws[128 * 32];

  const int z = blockIdx.z;
  const bfloat *A0, *A1 = nullptr, *Wm;
  bfloat *Oh, *Ol = nullptr;
  float scale = 1.f;
  bool split;
  if (z == 0) {
    A0 = xqh; A1 = xql; Wm = wqt; Oh = qmh; Ol = qml;
    scale = 0.18033688f;  // 1/sqrt(64) * log2(e), folded out of flash
    split = true;
  } else if (z == 1) {
    A0 = xkh; A1 = xkl; Wm = wkt; Oh = kmh; Ol = kml; split = true;
  } else {
    A0 = xvh; Wm = wvt; Oh = vmm; split = false;
  }

  const int t = threadIdx.x;
  const int w = t >> 6, lane = t & 63;
  const int quad = lane >> 4, l16 = lane & 15;
  const int wm = w >> 1, wn = w & 1;
  const int m0 = blockIdx.y * 128, n0 = blockIdx.x * 128;

  f32x4 acc[4][4] = {};

  const int sr = t >> 2;
  const int sc = (t & 3) * 8;

  const bfloat* pA0a = A0 + (size_t)(m0 + sr) * K + sc;
  const bfloat* pA0b = A0 + (size_t)(m0 + 64 + sr) * K + sc;
  const bfloat* pA1a = split ? A1 + (size_t)(m0 + sr) * K + sc : nullptr;
  const bfloat* pA1b = split ? A1 + (size_t)(m0 + 64 + sr) * K + sc : nullptr;
  const bfloat* pWa = Wm + (size_t)(n0 + sr) * K + sc;
  const bfloat* pWb = Wm + (size_t)(n0 + 64 + sr) * K + sc;

  for (int kk = 0; kk < K; kk += 32) {
    gl_lds16(pA0a + kk, As0 + w * 512);
    gl_lds16(pA0b + kk, As0 + 2048 + w * 512);
    if (split) {
      gl_lds16(pA1a + kk, As1 + w * 512);
      gl_lds16(pA1b + kk, As1 + 2048 + w * 512);
    }
    gl_lds16(pWa + kk, Ws + w * 512);
    gl_lds16(pWb + kk, Ws + 2048 + w * 512);
    __syncthreads();

    bf16x8 bfrag[4], afrag[4];
#pragma unroll
    for (int nt = 0; nt < 4; nt++)
      bfrag[nt] = *(const bf16x8*)&Ws[(wn * 64 + nt * 16 + l16) * 32 + quad * 8];
#pragma unroll
    for (int mt = 0; mt < 4; mt++)
      afrag[mt] = *(const bf16x8*)&As0[(wm * 64 + mt * 16 + l16) * 32 + quad * 8];
#pragma unroll
    for (int mt = 0; mt < 4; mt++)
#pragma unroll
      for (int nt = 0; nt < 4; nt++)
        acc[mt][nt] = MFMA_BF16(afrag[mt], bfrag[nt], acc[mt][nt]);
    if (split) {
#pragma unroll
      for (int mt = 0; mt < 4; mt++)
        afrag[mt] = *(const bf16x8*)&As1[(wm * 64 + mt * 16 + l16) * 32 + quad * 8];
#pragma unroll
      for (int mt = 0; mt < 4; mt++)
#pragma unroll
        for (int nt = 0; nt < 4; nt++)
          acc[mt][nt] = MFMA_BF16(afrag[mt], bfrag[nt], acc[mt][nt]);
    }
    __syncthreads();
  }

#pragma unroll
  for (int mt = 0; mt < 4; mt++) {
#pragma unroll
    for (int nt = 0; nt < 4; nt++) {
      const int row = m0 + wm * 64 + mt * 16 + quad * 4;
      const int col = n0 + wn * 64 + nt * 16 + l16;
#pragma unroll
      for (int rg = 0; rg < 4; rg++) {
        float vv = acc[mt][nt][rg] * scale;
        size_t idx = (size_t)(row + rg) * N + col;
        bfloat hh = (bfloat)vv;
        Oh[idx] = hh;
        if (split) Ol[idx] = (bfloat)(vv - (float)hh);
      }
    }
  }
}

// -------- W_O GEMM: 128x64 tile, grid (16,32)=512 blocks = 2/CU, fp32 out --
__global__ __launch_bounds__(256) void gemm_wo(const bfloat* __restrict__ A,
                                               const bfloat* __restrict__ Wm,
                                               float* __restrict__ Cf) {
  constexpr int K = D;
  constexpr int N = D;
  __shared__ __align__(16) bfloat As[128 * 32];
  __shared__ __align__(16) bfloat Ws[64 * 32];

  const int t = threadIdx.x;
  const int w = t >> 6, lane = t & 63;
  const int quad = lane >> 4, l16 = lane & 15;
  const int wm = w >> 1, wn = w & 1;
  const int m0 = blockIdx.y * 128, n0 = blockIdx.x * 64;

  f32x4 acc[4][2] = {};

  const int sr = t >> 2;
  const int sc = (t & 3) * 8;
  const bfloat* pAa = A + (size_t)(m0 + sr) * K + sc;
  const bfloat* pAb = A + (size_t)(m0 + 64 + sr) * K + sc;
  const bfloat* pW = Wm + (size_t)(n0 + sr) * K + sc;

  for (int kk = 0; kk < K; kk += 32) {
    gl_lds16(pAa + kk, As + w * 512);
    gl_lds16(pAb + kk, As + 2048 + w * 512);
    gl_lds16(pW + kk, Ws + w * 512);
    __syncthreads();

    bf16x8 bfrag[2], afrag[4];
#pragma unroll
    for (int nt = 0; nt < 2; nt++)
      bfrag[nt] = *(const bf16x8*)&Ws[(wn * 32 + nt * 16 + l16) * 32 + quad * 8];
#pragma unroll
    for (int mt = 0; mt < 4; mt++)
      afrag[mt] = *(const bf16x8*)&As[(wm * 64 + mt * 16 + l16) * 32 + quad * 8];
#pragma unroll
    for (int mt = 0; mt < 4; mt++)
#pragma unroll
      for (int nt = 0; nt < 2; nt++)
        acc[mt][nt] = MFMA_BF16(afrag[mt], bfrag[nt], acc[mt][nt]);
    __syncthreads();
  }

#pragma unroll
  for (int mt = 0; mt < 4; mt++) {
#pragma unroll
    for (int nt = 0; nt < 2; nt++) {
      const int row = m0 + wm * 64 + mt * 16 + quad * 4;
      const int col = n0 + wn * 32 + nt * 16 + l16;
#pragma unroll
      for (int rg = 0; rg < 4; rg++) Cf[(size_t)(row + rg) * N + col] = acc[mt][nt][rg];
    }
  }
}

// ---------------- flash attention v3 ----------------
// Q pre-scaled by 1/sqrt(64)*log2e (folded into q projection).
// l_i computed on the matrix pipe: Vt rows 64..79 are an all-ones tile; an
// extra PV MFMA accumulates per-row sums of bf16-P in C-layout (= l_i).
__global__ __launch_bounds__(256, 4) void flash_kernel(
    const bfloat* __restrict__ qh, const bfloat* __restrict__ ql,
    const bfloat* __restrict__ kh, const bfloat* __restrict__ kl,
    const bfloat* __restrict__ vt, bfloat* __restrict__ outp) {
  __shared__ __align__(16) bfloat Kh[64 * 64];
  __shared__ __align__(16) bfloat Kl[64 * 64];
  __shared__ __align__(16) bfloat Vt[80 * 64];  // rows 64..79 = 1.0
  __shared__ __align__(16) bfloat Pm[64 * 64];

  const int t = threadIdx.x;
  const int w = t >> 6, lane = t & 63;
  const int quad = lane >> 4, l16 = lane & 15;
  const int b = blockIdx.z, h = blockIdx.y;
  const int q0 = blockIdx.x * 64;
  const size_t base = (size_t)b * S * D + (size_t)h * DH;
  const size_t vbase = (size_t)b * D * S + (size_t)h * DH * S;

  const int ssr = lane >> 3;
  const int spc = lane & 7;

  {  // ones tile init (1024 elems, 4/thread); covered by the prologue barrier
    bf16x4 one = {(bfloat)1.f, (bfloat)1.f, (bfloat)1.f, (bfloat)1.f};
    *(bf16x4*)&Vt[64 * 64 + t * 4] = one;
  }
#pragma unroll
  for (int g = 0; g < 2; g++) {  // stage Q hi/lo through K buffers
    int r = w * 16 + g * 8 + ssr;
    int c = spc ^ (r & 7);
    int lo = (w * 16 + g * 8) * 64;
    gl_lds16(qh + base + (size_t)(q0 + r) * D + c * 8, Kh + lo);
    gl_lds16(ql + base + (size_t)(q0 + r) * D + c * 8, Kl + lo);
  }
  __syncthreads();
  bf16x8 ah[2], al[2];
  {
    int row = w * 16 + l16;
#pragma unroll
    for (int s2 = 0; s2 < 2; s2++) {
      ah[s2] = *(const bf16x8*)&Kh[row * 64 + (((s2 * 4 + quad) ^ (row & 7)) * 8)];
      al[s2] = *(const bf16x8*)&Kl[row * 64 + (((s2 * 4 + quad) ^ (row & 7)) * 8)];
    }
  }

  f32x4 Oa[4] = {};
  f32x4 La = {};
  float m_i[4];
#pragma unroll
  for (int i = 0; i < 4; i++) m_i[i] = -3.0e38f;

  for (int k0 = 0; k0 < S; k0 += 64) {
    __syncthreads();  // prev iter's frag reads (and prologue Q reads) done
#pragma unroll
    for (int g = 0; g < 2; g++) {
      int r = w * 16 + g * 8 + ssr;
      int c = spc ^ (r & 7);
      int lo = (w * 16 + g * 8) * 64;
      gl_lds16(kh + base + (size_t)(k0 + r) * D + c * 8, Kh + lo);
      gl_lds16(kl + base + (size_t)(k0 + r) * D + c * 8, Kl + lo);
      gl_lds16(vt + vbase + (size_t)r * S + k0 + c * 8, Vt + lo);
    }
    __syncthreads();

    // S = Qh*Kh + Ql*Kh + Qh*Kl (already scaled, log2 domain)
    f32x4 sf[4];
#pragma unroll
    for (int nt = 0; nt < 4; nt++) {
      f32x4 acc = {};
      int row = nt * 16 + l16;
#pragma unroll
      for (int s2 = 0; s2 < 2; s2++) {
        bf16x8 bh = *(const bf16x8*)&Kh[row * 64 + (((s2 * 4 + quad) ^ (row & 7)) * 8)];
        bf16x8 bl = *(const bf16x8*)&Kl[row * 64 + (((s2 * 4 + quad) ^ (row & 7)) * 8)];
        acc = MFMA_BF16(ah[s2], bh, acc);
        acc = MFMA_BF16(al[s2], bh, acc);
        acc = MFMA_BF16(ah[s2], bl, acc);
      }
      sf[nt] = acc;
    }

    // online softmax; row quad*4+rg lives on the 16 lanes of this quad
#pragma unroll
    for (int rg = 0; rg < 4; rg++) {
      float mm = fmaxf(fmaxf(sf[0][rg], sf[1][rg]), fmaxf(sf[2][rg], sf[3][rg]));
#pragma unroll
      for (int off = 1; off < 16; off <<= 1) mm = fmaxf(mm, __shfl_xor(mm, off, 64));
      float mnew = fmaxf(m_i[rg], mm);
      float alpha = exp2f(m_i[rg] - mnew);
      m_i[rg] = mnew;
#pragma unroll
      for (int nt = 0; nt < 4; nt++) sf[nt][rg] = exp2f(sf[nt][rg] - mnew);
#pragma unroll
      for (int nt = 0; nt < 4; nt++) Oa[nt][rg] *= alpha;
      La[rg] *= alpha;
    }

    // P: C-layout -> A-layout via wave-private LDS strip (swizzled)
#pragma unroll
    for (int nt = 0; nt < 4; nt++)
#pragma unroll
      for (int rg = 0; rg < 4; rg++) {
        int row = w * 16 + quad * 4 + rg;
        int col = nt * 16 + l16;
        Pm[row * 64 + (((col >> 3) ^ (row & 7)) * 8) + (col & 7)] = (bfloat)sf[nt][rg];
      }

    // O += P @ V ; La += P @ ones  (no barrier: Pm strip is wave-private)
    int prow = w * 16 + l16;
#pragma unroll
    for (int s2 = 0; s2 < 2; s2++) {
      bf16x8 pa = *(const bf16x8*)&Pm[prow * 64 + (((s2 * 4 + quad) ^ (prow & 7)) * 8)];
#pragma unroll
      for (int nt = 0; nt < 4; nt++) {
        int vrow = nt * 16 + l16;
        bf16x8 vb = *(const bf16x8*)&Vt[vrow * 64 + (((s2 * 4 + quad) ^ (vrow & 7)) * 8)];
        Oa[nt] = MFMA_BF16(pa, vb, Oa[nt]);
      }
      bf16x8 vb1 = *(const bf16x8*)&Vt[(64 + l16) * 64 + (((s2 * 4 + quad) ^ (l16 & 7)) * 8)];
      La = MFMA_BF16(pa, vb1, La);
    }
  }

#pragma unroll
  for (int rg = 0; rg < 4; rg++) {
    float inv = 1.0f / La[rg];
#pragma unroll
    for (int nt = 0; nt < 4; nt++) {
      outp[base + (size_t)(q0 + w * 16 + quad * 4 + rg) * D + nt * 16 + l16] =
          (bfloat)(Oa[nt][rg] * inv);
    }
  }
}

extern "C" void kernel_launch(void* const* d_in, const int* in_sizes, int n_in,
                              void* d_out, int out_size, void* d_ws, size_t ws_size,
                              hipStream_t stream) {
  const float* q_in = (const float*)d_in[0];
  const float* k_in = (const float*)d_in[1];
  const float* v_in = (const float*)d_in[2];
  const float* wq = (const float*)d_in[3];
  const float* wk = (const float*)d_in[4];
  const float* wv = (const float*)d_in[5];
  const float* wo = (const float*)d_in[6];
  float* outp = (float*)d_out;
  char* ws = (char*)d_ws;

  constexpr size_t WBYTES = (size_t)WMAT_N * 2;
  constexpr size_t XBYTES = (size_t)M * D * 2;
  size_t off = 0;
  double* sums = (double*)(ws + off); off += 256;
  bfloat* wqt = (bfloat*)(ws + off); off += WBYTES;
  bfloat* wkt = (bfloat*)(ws + off); off += WBYTES;
  bfloat* wvt = (bfloat*)(ws + off); off += WBYTES;
  bfloat* wot = (bfloat*)(ws + off); off += WBYTES;
  bfloat* xqh = (bfloat*)(ws + off); off += XBYTES;
  bfloat* xql = (bfloat*)(ws + off); off += XBYTES;
  bfloat* xkh = (bfloat*)(ws + off); off += XBYTES;
  bfloat* xkl = (bfloat*)(ws + off); off += XBYTES;
  bfloat* xvh = (bfloat*)(ws + off); off += XBYTES;
  bfloat* qmh = (bfloat*)(ws + off); off += XBYTES;
  bfloat* qml = (bfloat*)(ws + off); off += XBYTES;
  bfloat* kmh = (bfloat*)(ws + off); off += XBYTES;
  bfloat* kml = (bfloat*)(ws + off); off += XBYTES;
  bfloat* vmm = (bfloat*)(ws + off); off += XBYTES;
  bfloat* attn = xqh;  // dead after q projection
  bfloat* vtr = xvh;   // dead after v projection; reused for V^T [B][D][S]

  hipMemsetAsync(sums, 0, 4 * sizeof(double), stream);
  absum_kernel<<<dim3(128, 4), 256, 0, stream>>>(wq, wk, wv, wo, sums);
  tern_kernel<<<dim3(128, 4), 256, 0, stream>>>(wq, wk, wv, wo, wqt, wkt, wvt, wot, sums);
  splitcvt3_kernel<<<dim3(512, 3), 256, 0, stream>>>(q_in, k_in, v_in, xqh, xql, xkh, xkl, xvh);
  qkv_gemm<<<dim3(D / 128, M / 128, 3), 256, 0, stream>>>(
      xqh, xql, xkh, xkl, xvh, wqt, wkt, wvt, qmh, qml, kmh, kml, vmm);
  transpose_v<<<dim3(S / 64, D / 64, B), 256, 0, stream>>>(vmm, vtr);
  flash_kernel<<<dim3(S / 64, H, B), 256, 0, stream>>>(qmh, qml, kmh, kml, vtr, attn);
  gemm_wo<<<dim3(D / 64, M / 128), 256, 0, stream>>>(attn, wot, outp);
}